// Round 8
// baseline (1825.094 us; speedup 1.0000x reference)
//
#include <hip/hip_runtime.h>
#include <hip/hip_bf16.h>
#include <hip/hip_fp16.h>
#include <hip/hip_cooperative_groups.h>

namespace cg = cooperative_groups;

// ---------------------------------------------------------------------------
// GCN link predictor — cooperative mega-kernel (R20) with explicit
// agent-scope fences around every grid.sync, + host-side fallback to the
// proven R18 6-dispatch chain if the cooperative launch errors.
//   P1: bin (private bucket sort) || wprep (W^T fp16)
//   P2: csr (counting sort per bucket) || gemm1 h1 = X@W1 (unscaled)
//   P3: gather1 -> z1   P4: gemm2 -> h2   P5: gather2 -> z2   P6: decode
// R19 failure analysis: phase bodies == R18 (passed), so composition broke:
// (1) grid.sync alone gives no agent-scope visibility — dirty L2 lines in
//     producer XCD + stale per-CU L1 lines on re-used buf0/buf1 (G16);
//     fix: __threadfence() (L2 wb + L1 inv on gfx950) around each sync.
// (2) coop launch possibly rejected under graph capture -> zero output;
//     fix: check return code, fall back to R18 chain (same device bodies).
// R18: privatized binning (277.9 us). R17: dinv deferred into gather.
// R16: gather miss-path throughput-bound, 62 us floor, occupancy-insensitive.
// R13: row-major 256B rows only. R10-R12: keep gather unfused from gemm.
// ---------------------------------------------------------------------------

typedef _Float16 half8 __attribute__((ext_vector_type(8)));
typedef float floatx4 __attribute__((ext_vector_type(4)));

#define BK_SHIFT 8
#define BSC_EDGES 2048  // edges per bin vblock
#define SLAB_CAP 5120   // per-bucket capacity (mean 4092, sd 64, +16 sigma)
#define WPAD 136        // padded LDS row stride (halfs)
#define SMEM_BYTES (128 * WPAD * 2)   // 34816 B (gemm Wl is the max user)
#define GRID_BLKS 1024  // 4 blocks/CU x 256 CU (LDS 34816*4 <= 160K; VGPR<=128)

struct MegaParams {
    const float* x;
    const int* src;
    const int* dst;
    const int* eli;
    const float* W1; const float* b1;
    const float* W2; const float* b2;
    float* out;
    int* cnt; int* row_start; float* dinv;
    _Float16* WT1; _Float16* WT2;
    int* srcs; int* bins; int* P;
    _Float16* buf0; _Float16* buf1;
    int N, E, EL, NBK, NBIN, GB;
};

// ---- phase bodies (verbatim R18 logic) -----------------------------------

__device__ __forceinline__ void bin_body(int vb, const MegaParams& P_, char* smem, int tid) {
    int* lcnt  = (int*)smem;            // [1024]
    int* delta = (int*)(smem + 4096);   // [1024]
    int* ssum  = (int*)(smem + 8192);   // [256]
    int* stage = (int*)(smem + 9216);   // [2048]
    const int nbk = P_.NBK, E = P_.E;
    int e0 = vb * BSC_EDGES;
    int nloc = E - e0; if (nloc > BSC_EDGES) nloc = BSC_EDGES;

    for (int b = tid; b < nbk; b += 256) lcnt[b] = 0;
    __syncthreads();

    int d[BSC_EDGES / 256], s[BSC_EDGES / 256];
#pragma unroll
    for (int k = 0; k < BSC_EDGES / 256; ++k) {
        int e = e0 + k * 256 + tid;
        if (e < E) {
            d[k] = P_.dst[e];
            s[k] = P_.src[e];
            atomicAdd(&lcnt[d[k] >> BK_SHIFT], 1);
        } else d[k] = -1;
    }
    __syncthreads();

    const int gpb = (nbk + 255) >> 8;   // 2 for nbk=391
    int c[4], mysum = 0;
    for (int t = 0; t < gpb; ++t) {
        int b = tid * gpb + t;
        c[t] = (b < nbk) ? lcnt[b] : 0;
        mysum += c[t];
    }
    ssum[tid] = mysum;
    __syncthreads();
    for (int off = 1; off < 256; off <<= 1) {
        int t = (tid >= off) ? ssum[tid - off] : 0;
        __syncthreads();
        ssum[tid] += t;
        __syncthreads();
    }
    int base = ssum[tid] - mysum;
    for (int t = 0; t < gpb; ++t) {
        int b = tid * gpb + t;
        if (b < nbk) {
            delta[b] = base;
            lcnt[b] = base;
            base += c[t];
        }
    }
    __syncthreads();

#pragma unroll
    for (int k = 0; k < BSC_EDGES / 256; ++k) {
        if (d[k] >= 0) {
            int b = d[k] >> BK_SHIFT;
            int lp = atomicAdd(&lcnt[b], 1);
            stage[lp] = (s[k] << 8) | (d[k] & 255);
        }
    }
    __syncthreads();

    int* bb = P_.bins + (size_t)vb * BSC_EDGES;
    for (int j = tid; j < nloc; j += 256) bb[j] = stage[j];
    int prow = nbk + 1;
    int* pp = P_.P + (size_t)vb * prow;
    for (int b = tid; b <= nbk; b += 256)
        pp[b] = (b < nbk) ? delta[b] : nloc;
}

__device__ __forceinline__ void wprep_body(int b2, const MegaParams& P_, int tid) {
    if (tid < 128) {
        const float* W = (b2 < 128) ? P_.W1 : P_.W2;
        _Float16* WT = (b2 < 128) ? P_.WT1 : P_.WT2;
        int k = b2 & 127;
        WT[tid * 128 + k] = (_Float16)W[k * 128 + tid];
    }
}

__device__ __forceinline__ void csr_body(int b, const MegaParams& P_, char* smem, int tid) {
    int* stage = (int*)smem;            // [5120] 20480 B
    int* lcnt  = (int*)(smem + 20480);  // [256]
    int* lpos  = (int*)(smem + 21504);  // [256]
    int* curs  = (int*)(smem + 22528);  // [1]
    const int nbk = P_.NBK, nbin = P_.NBIN, n = P_.N;
    int prow = nbk + 1;
    if (tid == 0) *curs = 0;
    __syncthreads();
    for (int seg = tid; seg < nbin; seg += 256) {
        const int* pp = P_.P + (size_t)seg * prow + b;
        int p0 = pp[0], p1 = pp[1];
        int len = p1 - p0;
        if (len > 0) {
            int off = atomicAdd(curs, len);
            const int* sp = P_.bins + (size_t)seg * BSC_EDGES + p0;
            for (int i = 0; i < len; ++i) stage[off + i] = sp[i];
        }
    }
    __syncthreads();
    int tot = *curs;
    lcnt[tid] = 0;
    __syncthreads();
    for (int i = tid; i < tot; i += 256)
        atomicAdd(&lcnt[stage[i] & 255], 1);
    __syncthreads();
    int c = lcnt[tid];
    lpos[tid] = c;
    __syncthreads();
    for (int off = 1; off < 256; off <<= 1) {
        int t = (tid >= off) ? lpos[tid - off] : 0;
        __syncthreads();
        lpos[tid] += t;
        __syncthreads();
    }
    int rs = b * SLAB_CAP + lpos[tid] - c;
    int v = (b << BK_SHIFT) + tid;
    if (v < n) {
        P_.row_start[v] = rs;
        P_.cnt[v] = c;
        P_.dinv[v] = rsqrtf((float)c + 1.0f);
    }
    __syncthreads();
    lpos[tid] = rs;
    __syncthreads();
    for (int i = tid; i < tot; i += 256) {
        int p = stage[i];
        int loc = atomicAdd(&lpos[p & 255], 1);
        P_.srcs[loc] = p >> 8;
    }
}

template <typename AT>
__device__ __forceinline__ void gemm_body(int bid, const AT* __restrict__ X,
                                          const _Float16* __restrict__ WT,
                                          _Float16* __restrict__ G, int n,
                                          char* smem, int tid) {
    _Float16* Wl = (_Float16*)smem;     // [128 * WPAD]
    {
        const half8* w8 = (const half8*)WT;
#pragma unroll
        for (int i = 0; i < 8; ++i) {
            int idx = i * 256 + tid;
            int r = idx >> 4, cc = idx & 15;
            *(half8*)(Wl + r * WPAD + cc * 8) = w8[idx];
        }
    }
    __syncthreads();

    auto loadA = [](const AT* p) -> half8 {
        if constexpr (sizeof(AT) == 4) {
            const float4* f = (const float4*)p;
            float4 f0 = f[0], f1 = f[1];
            half8 a;
            a[0] = (_Float16)f0.x; a[1] = (_Float16)f0.y;
            a[2] = (_Float16)f0.z; a[3] = (_Float16)f0.w;
            a[4] = (_Float16)f1.x; a[5] = (_Float16)f1.y;
            a[6] = (_Float16)f1.z; a[7] = (_Float16)f1.w;
            return a;
        } else {
            return *(const half8*)p;
        }
    };

    int wave = tid >> 6, lane = tid & 63;
    int q = lane >> 4, ln = lane & 15;
    int m0 = bid * 128 + wave * 32;
    int mA0 = m0 + ln;      if (mA0 >= n) mA0 = n - 1;
    int mA1 = m0 + 16 + ln; if (mA1 >= n) mA1 = n - 1;
    const AT* xr0 = X + (size_t)mA0 * 128;
    const AT* xr1 = X + (size_t)mA1 * 128;

    floatx4 acc[2][8];
#pragma unroll
    for (int p = 0; p < 2; ++p)
#pragma unroll
        for (int t = 0; t < 8; ++t) acc[p][t] = (floatx4){0.f, 0.f, 0.f, 0.f};

#pragma unroll
    for (int kc = 0; kc < 128; kc += 32) {
        half8 a0 = loadA(xr0 + kc + q * 8);
        half8 a1 = loadA(xr1 + kc + q * 8);
#pragma unroll
        for (int t = 0; t < 8; ++t) {
            half8 b = *(const half8*)(Wl + (size_t)(t * 16 + ln) * WPAD + kc + q * 8);
            acc[0][t] = __builtin_amdgcn_mfma_f32_16x16x32_f16(a0, b, acc[0][t], 0, 0, 0);
            acc[1][t] = __builtin_amdgcn_mfma_f32_16x16x32_f16(a1, b, acc[1][t], 0, 0, 0);
        }
    }

#pragma unroll
    for (int p = 0; p < 2; ++p) {
#pragma unroll
        for (int r = 0; r < 4; ++r) {
            int row = m0 + p * 16 + q * 4 + r;
            if (row < n) {
                _Float16* grow = G + (size_t)row * 128 + ln;
#pragma unroll
                for (int t = 0; t < 8; ++t)
                    grow[t * 16] = (_Float16)acc[p][t][r];
            }
        }
    }
}

__device__ __forceinline__ void gather_phase(const _Float16* __restrict__ G,
                                             const float* __restrict__ bias,
                                             _Float16* __restrict__ Z,
                                             const MegaParams& P_, int nblk, int tid) {
    const int n = P_.N;
    const int nv = (n + 15) >> 4;
    const half8* G8 = (const half8*)G;
    int lane = tid & 15;
    const float4* b4 = (const float4*)bias;
    float4 bb0 = b4[lane * 2], bb1 = b4[lane * 2 + 1];
    float bf[8] = {bb0.x, bb0.y, bb0.z, bb0.w, bb1.x, bb1.y, bb1.z, bb1.w};

    for (int vb = blockIdx.x; vb < nv; vb += nblk) {
        int v = vb * 16 + (tid >> 4);
        if (v < n) {
            float dv = P_.dinv[v];
            half8 self = G8[(size_t)v * 16 + lane];
            float acc[8], acc2[8];
#pragma unroll
            for (int j = 0; j < 8; ++j) { acc[j] = dv * (float)self[j]; acc2[j] = 0.f; }

            int beg = P_.row_start[v], deg = P_.cnt[v];
            int e = 0;
            for (; e + 3 < deg; e += 4) {
                int s0 = P_.srcs[beg + e];
                int s1 = P_.srcs[beg + e + 1];
                int s2 = P_.srcs[beg + e + 2];
                int s3 = P_.srcs[beg + e + 3];
                float d0 = P_.dinv[s0];
                float d1 = P_.dinv[s1];
                float d2 = P_.dinv[s2];
                float d3 = P_.dinv[s3];
                half8 t0 = G8[(size_t)s0 * 16 + lane];
                half8 t1 = G8[(size_t)s1 * 16 + lane];
                half8 t2 = G8[(size_t)s2 * 16 + lane];
                half8 t3 = G8[(size_t)s3 * 16 + lane];
#pragma unroll
                for (int j = 0; j < 8; ++j) {
                    acc[j]  += d0 * (float)t0[j] + d1 * (float)t1[j];
                    acc2[j] += d2 * (float)t2[j] + d3 * (float)t3[j];
                }
            }
            for (; e < deg; ++e) {
                int s0 = P_.srcs[beg + e];
                float d0 = P_.dinv[s0];
                half8 t0 = G8[(size_t)s0 * 16 + lane];
#pragma unroll
                for (int j = 0; j < 8; ++j) acc[j] += d0 * (float)t0[j];
            }

            half8 zo;
#pragma unroll
            for (int j = 0; j < 8; ++j) {
                float z = dv * (acc[j] + acc2[j]) + bf[j];
                zo[j] = (_Float16)fmaxf(z, 0.f);
            }
            ((half8*)Z)[(size_t)v * 16 + lane] = zo;
        }
    }
}

__device__ __forceinline__ void decode_phase(const MegaParams& P_, int nblk, int tid) {
    const int el = P_.EL;
    const int nv = (el + 15) >> 4;
    const half8* Z8 = (const half8*)P_.buf1;
    int sub = tid >> 4, lane = tid & 15;
    for (int vb = blockIdx.x; vb < nv; vb += nblk) {
        int e = vb * 16 + sub;
        if (e < el) {
            int s = P_.eli[e], d = P_.eli[el + e];
            half8 a = Z8[(size_t)s * 16 + lane];
            half8 b = Z8[(size_t)d * 16 + lane];
            float dot = 0.f;
#pragma unroll
            for (int j = 0; j < 8; ++j) dot += (float)a[j] * (float)b[j];
#pragma unroll
            for (int off = 8; off; off >>= 1) dot += __shfl_down(dot, off, 16);
            if (lane == 0) P_.out[e] = dot;
        }
    }
}

// ---------------------------------------------------------------------------
// Mega-kernel with fenced grid syncs.
// ---------------------------------------------------------------------------
__global__ __launch_bounds__(256, 4) void k_mega(MegaParams P_) {
    cg::grid_group grid = cg::this_grid();
    __shared__ __align__(16) char smem[SMEM_BYTES];
    const int tid = threadIdx.x;
    const int nblk = gridDim.x;
    const int nbk = P_.NBK, nbin = P_.NBIN, gb = P_.GB;

    auto fence_sync = [&]() {
        __threadfence();   // release: L2 writeback to device scope
        grid.sync();
        __threadfence();   // acquire: invalidate L1 / stale L2 lines
    };

    // ---- P1: bin || wprep ----
    for (int vb = blockIdx.x; vb < nbin + 256; vb += nblk) {
        if (vb < nbin) bin_body(vb, P_, smem, tid);
        else wprep_body(vb - nbin, P_, tid);
        __syncthreads();
    }
    fence_sync();

    // ---- P2: csr || gemm1 ----
    for (int vb = blockIdx.x; vb < nbk + gb; vb += nblk) {
        if (vb < nbk) csr_body(vb, P_, smem, tid);
        else gemm_body<float>(vb - nbk, P_.x, P_.WT1, P_.buf0, P_.N, smem, tid);
        __syncthreads();
    }
    fence_sync();

    // ---- P3: gather1 -> z1 ----
    gather_phase(P_.buf0, P_.b1, P_.buf1, P_, nblk, tid);
    fence_sync();

    // ---- P4: gemm2 ----
    for (int vb = blockIdx.x; vb < gb; vb += nblk) {
        gemm_body<_Float16>(vb, P_.buf1, P_.WT2, P_.buf0, P_.N, smem, tid);
        __syncthreads();
    }
    fence_sync();

    // ---- P5: gather2 -> z2 ----
    gather_phase(P_.buf0, P_.b2, P_.buf1, P_, nblk, tid);
    fence_sync();

    // ---- P6: decode ----
    decode_phase(P_, nblk, tid);
}

// ---------------------------------------------------------------------------
// Fallback wrappers (R18 6-dispatch chain, same bodies).
// ---------------------------------------------------------------------------
__global__ __launch_bounds__(256) void k_bin_wprep(MegaParams P_) {
    __shared__ __align__(16) char smem[SMEM_BYTES];
    if ((int)blockIdx.x < P_.NBIN) bin_body(blockIdx.x, P_, smem, threadIdx.x);
    else wprep_body(blockIdx.x - P_.NBIN, P_, threadIdx.x);
}

__global__ __launch_bounds__(256) void k_csr_gemm1(MegaParams P_) {
    __shared__ __align__(16) char smem[SMEM_BYTES];
    if ((int)blockIdx.x < P_.NBK) csr_body(blockIdx.x, P_, smem, threadIdx.x);
    else gemm_body<float>(blockIdx.x - P_.NBK, P_.x, P_.WT1, P_.buf0, P_.N, smem, threadIdx.x);
}

__global__ __launch_bounds__(256) void k_gather(MegaParams P_, const float* bias) {
    gather_phase(P_.buf0, bias, P_.buf1, P_, gridDim.x, threadIdx.x);
}

__global__ __launch_bounds__(256) void k_gemm2(MegaParams P_) {
    __shared__ __align__(16) char smem[SMEM_BYTES];
    gemm_body<_Float16>(blockIdx.x, P_.buf1, P_.WT2, P_.buf0, P_.N, smem, threadIdx.x);
}

__global__ __launch_bounds__(256) void k_decode(MegaParams P_) {
    decode_phase(P_, gridDim.x, threadIdx.x);
}

extern "C" void kernel_launch(void* const* d_in, const int* in_sizes, int n_in,
                              void* d_out, int out_size, void* d_ws, size_t ws_size,
                              hipStream_t stream) {
    const float* x  = (const float*)d_in[0];
    const int*  ei  = (const int*)d_in[1];
    const int*  eli = (const int*)d_in[2];
    const float* W1 = (const float*)d_in[3];
    const float* b1 = (const float*)d_in[4];
    const float* W2 = (const float*)d_in[5];
    const float* b2 = (const float*)d_in[6];
    float* out = (float*)d_out;

    const int N  = in_sizes[0] / 128;
    const int E  = in_sizes[1] / 2;
    const int EL = in_sizes[2] / 2;
    const int NBK  = (N + 255) >> BK_SHIFT;                 // 391
    const int NBIN = (E + BSC_EDGES - 1) / BSC_EDGES;       // 782
    const int GB   = (N + 127) / 128;                       // 782

    char* ws = (char*)d_ws;
    size_t off = 0;
    auto alloc = [&](size_t bytes) -> void* {
        void* p = ws + off;
        off += bytes;
        off = (off + 255) & ~(size_t)255;
        return p;
    };
    int*       cnt       = (int*)alloc((size_t)N * 4);
    int*       row_start = (int*)alloc((size_t)N * 4);
    float*     dinv      = (float*)alloc((size_t)N * 4);
    _Float16*  WT1       = (_Float16*)alloc(128 * 128 * 2);
    _Float16*  WT2       = (_Float16*)alloc(128 * 128 * 2);
    int*       srcs      = (int*)alloc((size_t)NBK * SLAB_CAP * 4);
    int*       bins      = (int*)alloc((size_t)NBIN * BSC_EDGES * 4);
    int*       P         = (int*)alloc((size_t)NBIN * (NBK + 1) * 4);
    _Float16*  buf0      = (_Float16*)alloc((size_t)N * 128 * 2);  // h1 -> h2
    _Float16*  buf1      = (_Float16*)alloc((size_t)N * 128 * 2);  // z1 -> z2

    MegaParams mp;
    mp.x = x; mp.src = ei; mp.dst = ei + E; mp.eli = eli;
    mp.W1 = W1; mp.b1 = b1; mp.W2 = W2; mp.b2 = b2;
    mp.out = out;
    mp.cnt = cnt; mp.row_start = row_start; mp.dinv = dinv;
    mp.WT1 = WT1; mp.WT2 = WT2;
    mp.srcs = srcs; mp.bins = bins; mp.P = P;
    mp.buf0 = buf0; mp.buf1 = buf1;
    mp.N = N; mp.E = E; mp.EL = EL; mp.NBK = NBK; mp.NBIN = NBIN; mp.GB = GB;

    void* kargs[] = {(void*)&mp};
    hipError_t err = hipLaunchCooperativeKernel((const void*)k_mega, dim3(GRID_BLKS),
                                                dim3(256), kargs, 0, stream);
    if (err != hipSuccess) {
        (void)hipGetLastError();   // clear sticky error, fall back to R18 chain
        k_bin_wprep<<<NBIN + 256, 256, 0, stream>>>(mp);
        k_csr_gemm1<<<NBK + GB, 256, 0, stream>>>(mp);
        k_gather<<<(N + 15) / 16, 256, 0, stream>>>(mp, b1);
        k_gemm2<<<GB, 256, 0, stream>>>(mp);
        k_gather<<<(N + 15) / 16, 256, 0, stream>>>(mp, b2);
        k_decode<<<(EL + 15) / 16, 256, 0, stream>>>(mp);
    }
}

// Round 9
// 303.241 us; speedup vs baseline: 6.0186x; 6.0186x over previous
//
#include <hip/hip_runtime.h>
#include <hip/hip_bf16.h>
#include <hip/hip_fp16.h>

// ---------------------------------------------------------------------------
// GCN link predictor, fp16 intermediates + MFMA GEMMs (fp32 accumulate):
//   h1 = X @ W1                                  (MFMA GEMM, fp32 A, UNSCALED)
//   z1 = relu(dinv[v]*(dinv[v]*h1[v] + sum dinv[s]*h1[s]) + b1)   (gather)
//   h2 = z1 @ W2                                 (MFMA GEMM, fp16 A, UNSCALED)
//   z2 = relu(dinv[v]*(dinv[v]*h2[v] + sum dinv[s]*h2[s]) + b2)   (gather)
//   out[e] = dot(z2[s], z2[d])
//
// R21: REVERT to R18 chain (277.9 us proven). R19/R20 post-mortem: coop
// mega-kernel was CORRECT with __threadfence around grid.sync (G16 lesson:
// grid.sync alone gives no agent-scope visibility on non-coherent XCD L2s)
// but ran 6.25x SLOWER (1737 us, VALUBusy 3.1%, traffic normal) — runtime
// executes cooperative dispatches with heavily restricted concurrency.
// Cooperative launch is abandoned on this stack.
// R21 changes vs R18:
//   (a) each gather split into 2 half-dispatches (~31 us) so that any other
//       kernel >31 us becomes visible in top-5 (replays of the 62 us gathers
//       have monopolized it every round).
//   (b) csr phase-A segment pull 2-way interleaved (MLP on the scattered
//       load latency chain).
// R18: privatized binning (bin writes private coalesced segments; csr pulls
// + counting-sorts; no global atomics in binning). -29.7 us vs R17.
// R17: dinv deferred into gather; csr || gemm1 fused.
// R16: gather is THROUGHPUT-bound on L2-miss path (~3.6 TB/s service);
// +28% MLP = 0 gain; 61-62 us/gather structural floor; occupancy-insensitive.
// R13: row-major 256B rows only (32B column slices waste 4x on 128B lines).
// R10-R12: keep gather unfused from gemm (fused = 80-85 vs 61+13).
// ---------------------------------------------------------------------------

typedef _Float16 half8 __attribute__((ext_vector_type(8)));
typedef float floatx4 __attribute__((ext_vector_type(4)));

#define BK_SHIFT 8
#define BSC_EDGES 2048  // edges per bin block
#define SLAB_CAP 5120   // per-bucket capacity (mean 4092, sd 64, +16 sigma)
#define WPAD 136        // padded LDS row stride (halfs)

// ---------------------------------------------------------------------------
// k_bin: private bucket-sort of 2048 edges/block + weight-prep tail blocks.
// blocks [0, nbin): binning. blocks [nbin, nbin+256): wprep (128 lanes).
// ---------------------------------------------------------------------------
__global__ __launch_bounds__(256) void k_bin(const int* __restrict__ src,
                                             const int* __restrict__ dst,
                                             int* __restrict__ bins,
                                             int* __restrict__ P,
                                             int E, int nbk, int nbin,
                                             const float* __restrict__ W1,
                                             const float* __restrict__ W2,
                                             _Float16* __restrict__ WT1,
                                             _Float16* __restrict__ WT2) {
    int tid = threadIdx.x;
    if ((int)blockIdx.x >= nbin) {
        // ---- weight prep: transpose + fp16 cast (2 x 128x128) ----
        int b2 = blockIdx.x - nbin;          // 0..255
        if (tid < 128) {
            const float* W = (b2 < 128) ? W1 : W2;
            _Float16* WT = (b2 < 128) ? WT1 : WT2;
            int k = b2 & 127;
            WT[tid * 128 + k] = (_Float16)W[k * 128 + tid];
        }
        return;
    }

    __shared__ int lcnt[1024];    // counts -> fill cursor
    __shared__ int delta[1024];   // saved bucket base (intra-block offset)
    __shared__ int ssum[256];     // block-scan workspace
    __shared__ int stage[BSC_EDGES];
    int e0 = blockIdx.x * BSC_EDGES;
    int nloc = E - e0; if (nloc > BSC_EDGES) nloc = BSC_EDGES;

    for (int b = tid; b < nbk; b += 256) lcnt[b] = 0;
    __syncthreads();

    int d[BSC_EDGES / 256], s[BSC_EDGES / 256];
#pragma unroll
    for (int k = 0; k < BSC_EDGES / 256; ++k) {
        int e = e0 + k * 256 + tid;
        if (e < E) {
            d[k] = dst[e];
            s[k] = src[e];
            atomicAdd(&lcnt[d[k] >> BK_SHIFT], 1);
        } else d[k] = -1;
    }
    __syncthreads();

    const int gpb = (nbk + 255) >> 8;   // 2 for nbk=391
    int c[4], mysum = 0;
    for (int t = 0; t < gpb; ++t) {
        int b = tid * gpb + t;
        c[t] = (b < nbk) ? lcnt[b] : 0;
        mysum += c[t];
    }
    ssum[tid] = mysum;
    __syncthreads();
    for (int off = 1; off < 256; off <<= 1) {
        int t = (tid >= off) ? ssum[tid - off] : 0;
        __syncthreads();
        ssum[tid] += t;
        __syncthreads();
    }
    int base = ssum[tid] - mysum;
    for (int t = 0; t < gpb; ++t) {
        int b = tid * gpb + t;
        if (b < nbk) {
            delta[b] = base;
            lcnt[b] = base;
            base += c[t];
        }
    }
    __syncthreads();

#pragma unroll
    for (int k = 0; k < BSC_EDGES / 256; ++k) {
        if (d[k] >= 0) {
            int b = d[k] >> BK_SHIFT;
            int lp = atomicAdd(&lcnt[b], 1);
            stage[lp] = (s[k] << 8) | (d[k] & 255);
        }
    }
    __syncthreads();

    // private contiguous writes: fully coalesced, no sharing
    int* bb = bins + (size_t)blockIdx.x * BSC_EDGES;
    for (int j = tid; j < nloc; j += 256) bb[j] = stage[j];
    int prow = nbk + 1;
    int* pp = P + (size_t)blockIdx.x * prow;
    for (int b = tid; b <= nbk; b += 256)
        pp[b] = (b < nbk) ? delta[b] : nloc;
}

// ---------------------------------------------------------------------------
// FUSED: csr-build (blocks 0..nbk-1) || gemm1 (blocks nbk..nbk+gb-1).
// csr path: pull bucket b's edges from nbin private segments into LDS
// (2-way interleaved for MLP), then counting sort -> srcs slab.
// gemm path: unscaled (N x 128)@(128 x 128), 34.8 KB LDS (union'd).
// ---------------------------------------------------------------------------
template <typename AT>
__global__ __launch_bounds__(256) void k_csr_gemm(const int* __restrict__ bins,
                                                  const int* __restrict__ P,
                                                  int* __restrict__ row_start,
                                                  int* __restrict__ cnt,
                                                  float* __restrict__ dinv,
                                                  int* __restrict__ srcs,
                                                  const AT* __restrict__ X,
                                                  const _Float16* __restrict__ WT,
                                                  _Float16* __restrict__ G,
                                                  int n, int nbk, int nbin) {
    __shared__ __align__(16) char smem[128 * WPAD * 2];   // 34816 B union
    int tid = threadIdx.x;

    if ((int)blockIdx.x < nbk) {
        // ---------------- CSR path ----------------
        int* stage = (int*)smem;                    // [SLAB_CAP] 20480 B
        int* lcnt  = (int*)(smem + 20480);          // [256]
        int* lpos  = (int*)(smem + 21504);          // [256]
        int* curs  = (int*)(smem + 22528);          // [1]
        int b = blockIdx.x;
        int prow = nbk + 1;
        if (tid == 0) *curs = 0;
        __syncthreads();
        // phase A: pull my bucket's edges from private segments into LDS.
        // 2-way interleaved (seg, seg+half): doubles outstanding scattered
        // loads on the latency chain (R21).
        int half = (nbin + 1) >> 1;
        for (int seg = tid; seg < half; seg += 256) {
            const int* ppA = P + (size_t)seg * prow + b;
            int a0 = ppA[0], a1 = ppA[1];
            int segB = seg + half;
            int b0 = 0, b1 = 0;
            if (segB < nbin) {
                const int* ppB = P + (size_t)segB * prow + b;
                b0 = ppB[0]; b1 = ppB[1];
            }
            int lenA = a1 - a0, lenB = b1 - b0;
            int offA = lenA > 0 ? atomicAdd(curs, lenA) : 0;
            int offB = lenB > 0 ? atomicAdd(curs, lenB) : 0;
            const int* spA = bins + (size_t)seg * BSC_EDGES + a0;
            const int* spB = bins + (size_t)segB * BSC_EDGES + b0;
            int m = lenA > lenB ? lenA : lenB;
            for (int i = 0; i < m; ++i) {
                if (i < lenA) stage[offA + i] = spA[i];
                if (i < lenB) stage[offB + i] = spB[i];
            }
        }
        __syncthreads();
        int tot = *curs;
        // phase B: counting sort over 256 dst slots
        lcnt[tid] = 0;
        __syncthreads();
        for (int i = tid; i < tot; i += 256)
            atomicAdd(&lcnt[stage[i] & 255], 1);
        __syncthreads();
        int c = lcnt[tid];
        lpos[tid] = c;
        __syncthreads();
        for (int off = 1; off < 256; off <<= 1) {
            int t = (tid >= off) ? lpos[tid - off] : 0;
            __syncthreads();
            lpos[tid] += t;
            __syncthreads();
        }
        int rs = b * SLAB_CAP + lpos[tid] - c;   // row start in srcs slab
        int v = (b << BK_SHIFT) + tid;
        if (v < n) {
            row_start[v] = rs;
            cnt[v] = c;
            dinv[v] = rsqrtf((float)c + 1.0f);
        }
        __syncthreads();
        lpos[tid] = rs;                 // reuse as fill cursor
        __syncthreads();
        for (int i = tid; i < tot; i += 256) {
            int p = stage[i];
            int loc = atomicAdd(&lpos[p & 255], 1);
            srcs[loc] = p >> 8;
        }
        return;
    }

    // ---------------- GEMM path (unscaled epilogue) ----------------
    _Float16* Wl = (_Float16*)smem;    // [128 * WPAD]
    {
        const half8* w8 = (const half8*)WT;
#pragma unroll
        for (int i = 0; i < 8; ++i) {
            int idx = i * 256 + tid;
            int r = idx >> 4, cc = idx & 15;
            *(half8*)(Wl + r * WPAD + cc * 8) = w8[idx];
        }
    }
    __syncthreads();

    auto loadA = [](const AT* p) -> half8 {
        if constexpr (sizeof(AT) == 4) {
            const float4* f = (const float4*)p;
            float4 f0 = f[0], f1 = f[1];
            half8 a;
            a[0] = (_Float16)f0.x; a[1] = (_Float16)f0.y;
            a[2] = (_Float16)f0.z; a[3] = (_Float16)f0.w;
            a[4] = (_Float16)f1.x; a[5] = (_Float16)f1.y;
            a[6] = (_Float16)f1.z; a[7] = (_Float16)f1.w;
            return a;
        } else {
            return *(const half8*)p;
        }
    };

    int bid = blockIdx.x - nbk;
    int wave = tid >> 6, lane = tid & 63;
    int q = lane >> 4, ln = lane & 15;
    int m0 = bid * 128 + wave * 32;
    int mA0 = m0 + ln;      if (mA0 >= n) mA0 = n - 1;
    int mA1 = m0 + 16 + ln; if (mA1 >= n) mA1 = n - 1;
    const AT* xr0 = X + (size_t)mA0 * 128;
    const AT* xr1 = X + (size_t)mA1 * 128;

    floatx4 acc[2][8];
#pragma unroll
    for (int p = 0; p < 2; ++p)
#pragma unroll
        for (int t = 0; t < 8; ++t) acc[p][t] = (floatx4){0.f, 0.f, 0.f, 0.f};

#pragma unroll
    for (int kc = 0; kc < 128; kc += 32) {
        half8 a0 = loadA(xr0 + kc + q * 8);
        half8 a1 = loadA(xr1 + kc + q * 8);
#pragma unroll
        for (int t = 0; t < 8; ++t) {
            half8 b = *(const half8*)(Wl + (size_t)(t * 16 + ln) * WPAD + kc + q * 8);
            acc[0][t] = __builtin_amdgcn_mfma_f32_16x16x32_f16(a0, b, acc[0][t], 0, 0, 0);
            acc[1][t] = __builtin_amdgcn_mfma_f32_16x16x32_f16(a1, b, acc[1][t], 0, 0, 0);
        }
    }

#pragma unroll
    for (int p = 0; p < 2; ++p) {
#pragma unroll
        for (int r = 0; r < 4; ++r) {
            int row = m0 + p * 16 + q * 4 + r;
            if (row < n) {
                _Float16* grow = G + (size_t)row * 128 + ln;
#pragma unroll
                for (int t = 0; t < 8; ++t)
                    grow[t * 16] = (_Float16)acc[p][t][r];
            }
        }
    }
}

// ---------------------------------------------------------------------------
// Standalone unscaled GEMM (layer 2).
// ---------------------------------------------------------------------------
template <typename AT>
__global__ __launch_bounds__(256) void k_gemm_mfma(const AT* __restrict__ X,
                                                   const _Float16* __restrict__ WT,
                                                   _Float16* __restrict__ G, int n) {
    __shared__ _Float16 Wl[128 * WPAD];
    int tid = threadIdx.x;
    {
        const half8* w8 = (const half8*)WT;
#pragma unroll
        for (int i = 0; i < 8; ++i) {
            int idx = i * 256 + tid;
            int r = idx >> 4, cc = idx & 15;
            *(half8*)(Wl + r * WPAD + cc * 8) = w8[idx];
        }
    }
    __syncthreads();

    auto loadA = [](const AT* p) -> half8 {
        if constexpr (sizeof(AT) == 4) {
            const float4* f = (const float4*)p;
            float4 f0 = f[0], f1 = f[1];
            half8 a;
            a[0] = (_Float16)f0.x; a[1] = (_Float16)f0.y;
            a[2] = (_Float16)f0.z; a[3] = (_Float16)f0.w;
            a[4] = (_Float16)f1.x; a[5] = (_Float16)f1.y;
            a[6] = (_Float16)f1.z; a[7] = (_Float16)f1.w;
            return a;
        } else {
            return *(const half8*)p;
        }
    };

    int wave = tid >> 6, lane = tid & 63;
    int q = lane >> 4, ln = lane & 15;
    int m0 = blockIdx.x * 128 + wave * 32;
    int mA0 = m0 + ln;      if (mA0 >= n) mA0 = n - 1;
    int mA1 = m0 + 16 + ln; if (mA1 >= n) mA1 = n - 1;
    const AT* xr0 = X + (size_t)mA0 * 128;
    const AT* xr1 = X + (size_t)mA1 * 128;

    floatx4 acc[2][8];
#pragma unroll
    for (int p = 0; p < 2; ++p)
#pragma unroll
        for (int t = 0; t < 8; ++t) acc[p][t] = (floatx4){0.f, 0.f, 0.f, 0.f};

#pragma unroll
    for (int kc = 0; kc < 128; kc += 32) {
        half8 a0 = loadA(xr0 + kc + q * 8);
        half8 a1 = loadA(xr1 + kc + q * 8);
#pragma unroll
        for (int t = 0; t < 8; ++t) {
            half8 b = *(const half8*)(Wl + (size_t)(t * 16 + ln) * WPAD + kc + q * 8);
            acc[0][t] = __builtin_amdgcn_mfma_f32_16x16x32_f16(a0, b, acc[0][t], 0, 0, 0);
            acc[1][t] = __builtin_amdgcn_mfma_f32_16x16x32_f16(a1, b, acc[1][t], 0, 0, 0);
        }
    }

#pragma unroll
    for (int p = 0; p < 2; ++p) {
#pragma unroll
        for (int r = 0; r < 4; ++r) {
            int row = m0 + p * 16 + q * 4 + r;
            if (row < n) {
                _Float16* grow = G + (size_t)row * 128 + ln;
#pragma unroll
                for (int t = 0; t < 8; ++t)
                    grow[t * 16] = (_Float16)acc[p][t][r];
            }
        }
    }
}

// ---------------------------------------------------------------------------
// Gather + bias + relu -> Z (fp16). 16 lanes/node, half8 rows, fp32 accum.
// Per-edge dinv[s] scaling (deferred from gemm). 4-deep unroll (R0 proven;
// R16: deeper unroll neutral — miss-path throughput bound).
// R21: processes node range [vbase, vbase+vcnt) so each gather runs as two
// ~31 us half-dispatches (top-5 visibility for the other kernels).
// ---------------------------------------------------------------------------
__global__ __launch_bounds__(256) void k_gather_relu(const _Float16* __restrict__ G,
                                                     const int* __restrict__ srcs,
                                                     const int* __restrict__ row_start,
                                                     const int* __restrict__ cnt,
                                                     const float* __restrict__ dinv,
                                                     const float* __restrict__ bias,
                                                     _Float16* __restrict__ Z,
                                                     int vbase, int vcnt) {
    int v = vbase + blockIdx.x * 16 + (threadIdx.x >> 4);
    int lane = threadIdx.x & 15;
    if (v >= vbase + vcnt) return;
    const half8* G8 = (const half8*)G;

    float dv = dinv[v];
    half8 self = G8[(size_t)v * 16 + lane];
    float acc[8], acc2[8];
#pragma unroll
    for (int j = 0; j < 8; ++j) { acc[j] = dv * (float)self[j]; acc2[j] = 0.f; }

    int beg = row_start[v], deg = cnt[v];
    int e = 0;
    for (; e + 3 < deg; e += 4) {
        int s0 = srcs[beg + e];
        int s1 = srcs[beg + e + 1];
        int s2 = srcs[beg + e + 2];
        int s3 = srcs[beg + e + 3];
        float d0 = dinv[s0];
        float d1 = dinv[s1];
        float d2 = dinv[s2];
        float d3 = dinv[s3];
        half8 t0 = G8[(size_t)s0 * 16 + lane];
        half8 t1 = G8[(size_t)s1 * 16 + lane];
        half8 t2 = G8[(size_t)s2 * 16 + lane];
        half8 t3 = G8[(size_t)s3 * 16 + lane];
#pragma unroll
        for (int j = 0; j < 8; ++j) {
            acc[j]  += d0 * (float)t0[j] + d1 * (float)t1[j];
            acc2[j] += d2 * (float)t2[j] + d3 * (float)t3[j];
        }
    }
    for (; e < deg; ++e) {
        int s0 = srcs[beg + e];
        float d0 = dinv[s0];
        half8 t0 = G8[(size_t)s0 * 16 + lane];
#pragma unroll
        for (int j = 0; j < 8; ++j) acc[j] += d0 * (float)t0[j];
    }

    const float4* b4 = (const float4*)bias;
    float4 bb0 = b4[lane * 2], bb1 = b4[lane * 2 + 1];
    float bf[8] = {bb0.x, bb0.y, bb0.z, bb0.w, bb1.x, bb1.y, bb1.z, bb1.w};
    half8 zo;
#pragma unroll
    for (int j = 0; j < 8; ++j) {
        float z = dv * (acc[j] + acc2[j]) + bf[j];
        zo[j] = (_Float16)fmaxf(z, 0.f);
    }
    ((half8*)Z)[(size_t)v * 16 + lane] = zo;
}

// ---------------------------------------------------------------------------
// Decode: out[e] = dot(Z[s_e], Z[d_e]) over 128 dims (fp16 rows, fp32 accum).
// ---------------------------------------------------------------------------
__global__ __launch_bounds__(256) void k_decode(const _Float16* __restrict__ Z,
                                                const int* __restrict__ eli,
                                                float* __restrict__ out, int el) {
    int sub = threadIdx.x >> 4, lane = threadIdx.x & 15;
    int e = blockIdx.x * 16 + sub;
    if (e >= el) return;
    int s = eli[e], d = eli[el + e];
    const half8* Z8 = (const half8*)Z;
    half8 a = Z8[(size_t)s * 16 + lane];
    half8 b = Z8[(size_t)d * 16 + lane];
    float dot = 0.f;
#pragma unroll
    for (int j = 0; j < 8; ++j) dot += (float)a[j] * (float)b[j];
#pragma unroll
    for (int off = 8; off; off >>= 1) dot += __shfl_down(dot, off, 16);
    if (lane == 0) out[e] = dot;
}

extern "C" void kernel_launch(void* const* d_in, const int* in_sizes, int n_in,
                              void* d_out, int out_size, void* d_ws, size_t ws_size,
                              hipStream_t stream) {
    const float* x  = (const float*)d_in[0];
    const int*  ei  = (const int*)d_in[1];
    const int*  eli = (const int*)d_in[2];
    const float* W1 = (const float*)d_in[3];
    const float* b1 = (const float*)d_in[4];
    const float* W2 = (const float*)d_in[5];
    const float* b2 = (const float*)d_in[6];
    float* out = (float*)d_out;

    const int N  = in_sizes[0] / 128;
    const int E  = in_sizes[1] / 2;
    const int EL = in_sizes[2] / 2;
    const int* src = ei;
    const int* dst = ei + E;
    const int NBK  = (N + 255) >> BK_SHIFT;                 // 391
    const int NBIN = (E + BSC_EDGES - 1) / BSC_EDGES;       // 782
    const int GB   = (N + 127) / 128;                       // 782

    char* ws = (char*)d_ws;
    size_t off = 0;
    auto alloc = [&](size_t bytes) -> void* {
        void* p = ws + off;
        off += bytes;
        off = (off + 255) & ~(size_t)255;
        return p;
    };
    int*       cnt       = (int*)alloc((size_t)N * 4);
    int*       row_start = (int*)alloc((size_t)N * 4);
    float*     dinv      = (float*)alloc((size_t)N * 4);
    _Float16*  WT1       = (_Float16*)alloc(128 * 128 * 2);
    _Float16*  WT2       = (_Float16*)alloc(128 * 128 * 2);
    int*       srcs      = (int*)alloc((size_t)NBK * SLAB_CAP * 4);
    int*       bins      = (int*)alloc((size_t)NBIN * BSC_EDGES * 4);
    int*       P         = (int*)alloc((size_t)NBIN * (NBK + 1) * 4);
    _Float16*  buf0      = (_Float16*)alloc((size_t)N * 128 * 2);  // h1 -> h2
    _Float16*  buf1      = (_Float16*)alloc((size_t)N * 128 * 2);  // z1 -> z2

    // gather halves: [0, NH) and [NH, N), NH multiple of 16
    const int NH = ((N / 2) + 15) & ~15;
    const int G1 = (NH + 15) / 16;
    const int G2 = (N - NH + 15) / 16;

    // private binning (+ weight prep in tail blocks)
    k_bin<<<NBIN + 256, 256, 0, stream>>>(src, dst, bins, P, E, NBK, NBIN,
                                          W1, W2, WT1, WT2);

    // fused: csr (391 blocks) || gemm1 h1 = x@W1 -> buf0 (782 blocks)
    k_csr_gemm<float><<<NBK + GB, 256, 0, stream>>>(bins, P, row_start, cnt, dinv,
                                                    srcs, x, WT1, buf0, N, NBK, NBIN);

    // z1 = relu(dinv*(dinv*h1[v] + sum dinv[s]*h1[s]) + b1) -> buf1 (2 halves)
    k_gather_relu<<<G1, 256, 0, stream>>>(buf0, srcs, row_start, cnt, dinv, b1, buf1, 0, NH);
    k_gather_relu<<<G2, 256, 0, stream>>>(buf0, srcs, row_start, cnt, dinv, b1, buf1, NH, N - NH);
    // layer 2: h2 = z1@W2 -> buf0 ; z2 -> buf1 (2 halves)
    k_gemm_mfma<_Float16><<<GB, 256, 0, stream>>>(buf1, WT2, buf0, N);
    k_gather_relu<<<G1, 256, 0, stream>>>(buf0, srcs, row_start, cnt, dinv, b2, buf1, 0, NH);
    k_gather_relu<<<G2, 256, 0, stream>>>(buf0, srcs, row_start, cnt, dinv, b2, buf1, NH, N - NH);
    // decode
    k_decode<<<(EL + 15) / 16, 256, 0, stream>>>(buf1, eli, out, EL);
}